// Round 7
// baseline (199.545 us; speedup 1.0000x reference)
//
#include <hip/hip_runtime.h>
#include <cstdint>
#include <cstddef>

constexpr int Bn = 64;     // batch
constexpr int Nn = 1024;   // nodes per graph
constexpr int Dn = 1024;   // input feature dim
constexpr int Cn = 128;    // hidden channels
constexpr int En = 16384;  // edges per graph

typedef short s16x8 __attribute__((ext_vector_type(8)));   // 8 bf16 = 4 VGPR (MFMA A/B frag)
typedef float f32x4 __attribute__((ext_vector_type(4)));   // MFMA C/D frag

__device__ __forceinline__ uint32_t f2bf(float f) {        // fp32 -> bf16 bits, RNE
    uint32_t u = __float_as_uint(f);
    return (u + 0x7fffu + ((u >> 16) & 1u)) >> 16;
}

// ---------------- prep: zero indeg | int64-detect | Wc -> bf16 transposed ----------------
// blocks 0..3: zero indeg; 4..67: detect; 68..131: wconv.
// meta[1]==1 iff int32 edge data detected (ws poisoned 0xAA; all writers store 1 -> benign race).
__global__ __launch_bounds__(256) void k_prep(const int* __restrict__ ei32,
                                              const float* __restrict__ Wc,
                                              int* __restrict__ indeg,
                                              int* __restrict__ meta,
                                              unsigned short* __restrict__ Wt) {
    int bid = blockIdx.x, tid = threadIdx.x;
    if (bid < 4) {
        indeg[bid * 256 + tid] = 0;
    } else if (bid < 68) {
        __shared__ int sh;
        if (tid == 0) sh = 0;
        __syncthreads();
        int i = (bid - 4) * 256 + tid;          // [0, 16384)
        if (ei32[2 * i + 1]) atomicOr(&sh, 1);
        __syncthreads();
        if (tid == 0 && sh) meta[1] = 1;
    } else {
        int i = (bid - 68) * 256 + tid;         // [0, 16384)
        int n = i >> 7, k = i & 127;
        Wt[i] = (unsigned short)f2bf(Wc[k * Cn + n]);
    }
}

__global__ void k_hist(const int* __restrict__ ei32, const int* __restrict__ meta,
                       int* __restrict__ indeg) {
    int e = blockIdx.x * 256 + threadIdx.x;
    bool i64 = (meta[1] != 1);
    int dst = ei32[i64 ? 2 * (En + e) : (En + e)] & (Nn - 1);
    atomicAdd(&indeg[dst], 1);
}

__global__ __launch_bounds__(1024) void k_scan(const int* __restrict__ indeg,
                                               int* __restrict__ offs,
                                               int* __restrict__ cursor) {
    __shared__ int tmp[Nn];
    int t = threadIdx.x;
    int v = indeg[t];
    tmp[t] = v;
    __syncthreads();
    for (int off = 1; off < Nn; off <<= 1) {
        int add = (t >= off) ? tmp[t - off] : 0;
        __syncthreads();
        tmp[t] += add;
        __syncthreads();
    }
    offs[t + 1] = tmp[t];
    if (t == 0) offs[0] = 0;
    cursor[t] = tmp[t] - v;   // exclusive prefix
}

__global__ void k_scatter(const int* __restrict__ ei32, const int* __restrict__ meta,
                          int* __restrict__ cursor, int* __restrict__ ssrc) {
    int e = blockIdx.x * 256 + threadIdx.x;
    bool i64 = (meta[1] != 1);
    int src = ei32[i64 ? 2 * e : e] & (Nn - 1);
    int dst = ei32[i64 ? 2 * (En + e) : (En + e)] & (Nn - 1);
    int pos = atomicAdd(&cursor[dst], 1);
    if (pos >= 0 && pos < En) ssrc[pos] = src;
}

// ---------------- frontier build: F3 = in-neighbors(node0); F2 = in-neighbors(F3) ----------------
// single block; meta[2]=|F3|, meta[3]=|F2|
__global__ __launch_bounds__(1024) void k_levels(const int* __restrict__ offs,
                                                 const int* __restrict__ ssrc,
                                                 int* __restrict__ L3,
                                                 int* __restrict__ L2,
                                                 int* __restrict__ meta) {
    __shared__ int sf3[Nn];
    __shared__ int sf2[Nn];
    __shared__ int c3, c2;
    int t = threadIdx.x;
    sf3[t] = 0; sf2[t] = 0;
    if (t == 0) { c3 = 0; c2 = 0; }
    __syncthreads();
    int e1 = offs[1];                         // edges into node 0 are [0, offs[1])
    for (int e = t; e < e1; e += 1024) sf3[ssrc[e]] = 1;
    __syncthreads();
    if (sf3[t]) {
        int lo = offs[t], hi = offs[t + 1];
        for (int e = lo; e < hi; ++e) sf2[ssrc[e]] = 1;
    }
    __syncthreads();
    if (sf3[t]) { int p = atomicAdd(&c3, 1); L3[p] = t; }
    if (sf2[t]) { int p = atomicAdd(&c2, 1); L2[p] = t; }
    __syncthreads();
    if (t == 0) { meta[2] = c3; meta[3] = c2; }
}

// ---------------- embedding stage A: partial dots ----------------
__global__ __launch_bounds__(256) void k_embedA(const float* __restrict__ x,
                                                const float* __restrict__ We,
                                                float* __restrict__ pws) {
    __shared__ float sx[256];
    __shared__ float sp[256];
    int bid = blockIdx.x, tid = threadIdx.x;
    int b = bid >> 2, q = bid & 3;
    int c = tid & 127, h2 = tid >> 7;
    sx[tid] = x[b * Dn + q * 256 + tid];
    __syncthreads();
    float acc = 0.f;
    int d0 = q * 256 + h2 * 128;
    int dl = h2 * 128;
#pragma unroll 8
    for (int i = 0; i < 128; ++i) acc += sx[dl + i] * We[(d0 + i) * Cn + c];
    sp[h2 * 128 + c] = acc;
    __syncthreads();
    if (h2 == 0) pws[(b * 4 + q) * Cn + c] = sp[c] + sp[128 + c];
}

// ---------------- stage B: g = (relu(sum partials + be)) @ Wc ----------------
__global__ __launch_bounds__(128) void k_g(const float* __restrict__ pws,
                                           const float* __restrict__ be,
                                           const float* __restrict__ Wc,
                                           float* __restrict__ g) {
    __shared__ float se[Cn];
    int b = blockIdx.x, c = threadIdx.x;
    float e = pws[(b * 4 + 0) * Cn + c] + pws[(b * 4 + 1) * Cn + c] +
              pws[(b * 4 + 2) * Cn + c] + pws[(b * 4 + 3) * Cn + c] + be[c];
    se[c] = fmaxf(e, 0.f);
    __syncthreads();
    float ga = 0.f;
#pragma unroll 8
    for (int k = 0; k < Cn; ++k) ga += se[k] * Wc[k * Cn + c];
    g[b * Cn + c] = ga;
}

constexpr int PAD = 136;     // LDS row stride in bf16 elems

// ---------------- conv 1+2 fused, frontier-restricted:
// for dst in L2-tile: agg[c] = sum_{e into dst} relu(indeg[src_e]*g[b,c]+bc[c]);
// h2[b,dst,:] = relu(agg @ Wc + bc)  (fp32, scattered by node id) ----------------
__global__ __launch_bounds__(256, 4) void k_conv2L(const float* __restrict__ g,
                                                   float* __restrict__ h2,
                                                   const unsigned short* __restrict__ Wt,
                                                   const float* __restrict__ bc,
                                                   const int* __restrict__ indeg,
                                                   const int* __restrict__ offs,
                                                   const int* __restrict__ ssrc,
                                                   const int* __restrict__ L2,
                                                   const int* __restrict__ meta) {
    int cnt2 = meta[3];
    int bidx = blockIdx.x;
    int b = bidx >> 5, tile = bidx & 31;
    if (tile * 32 >= cnt2) return;
    __shared__ float sdeg[Nn];                 // 4 KB
    __shared__ unsigned short sSb[32 * PAD];   // 8.7 KB
    __shared__ int snode[32];
    int tid = threadIdx.x;
    for (int i = tid; i < Nn; i += 256) sdeg[i] = (float)indeg[i];
    if (tid < 32) {
        int ti = tile * 32 + tid;
        snode[tid] = (ti < cnt2) ? L2[ti] : -1;
    }
    __syncthreads();

    int c2 = tid & 63, u = tid >> 6;
    float gx = g[b * Cn + 2 * c2], gy = g[b * Cn + 2 * c2 + 1];
    float bx = bc[2 * c2], by = bc[2 * c2 + 1];
#pragma unroll
    for (int t0 = 0; t0 < 8; ++t0) {
        int row = u * 8 + t0;
        int node = snode[row];
        float s0 = 0.f, s1 = 0.f;
        if (node >= 0) {
            int lo = offs[node], hi = offs[node + 1];
            for (int j = lo; j < hi; ++j) {
                float d = sdeg[ssrc[j]];
                s0 += fmaxf(fmaf(d, gx, bx), 0.f);
                s1 += fmaxf(fmaf(d, gy, by), 0.f);
            }
        }
        *(uint32_t*)&sSb[row * PAD + 2 * c2] = f2bf(s0) | (f2bf(s1) << 16);
    }

    // B-fragments from global Wt (32 KB, L2-hot)
    int lane = tid & 63, w = tid >> 6;
    int m = lane & 15, quad = lane >> 4;
    s16x8 bf0[4], bf1[4];
#pragma unroll
    for (int ks = 0; ks < 4; ++ks) {
        int ko = ks * 32 + quad * 8;
        bf0[ks] = *(const s16x8*)&Wt[(w * 32 + m) * Cn + ko];
        bf1[ks] = *(const s16x8*)&Wt[(w * 32 + 16 + m) * Cn + ko];
    }
    __syncthreads();

    f32x4 acc[2][2];
#pragma unroll
    for (int rt = 0; rt < 2; ++rt)
#pragma unroll
        for (int ct = 0; ct < 2; ++ct) acc[rt][ct] = (f32x4){0.f, 0.f, 0.f, 0.f};
#pragma unroll
    for (int ks = 0; ks < 4; ++ks) {
        int ko = ks * 32 + quad * 8;
        s16x8 a0 = *(const s16x8*)&sSb[(0 * 16 + m) * PAD + ko];
        s16x8 a1 = *(const s16x8*)&sSb[(1 * 16 + m) * PAD + ko];
        acc[0][0] = __builtin_amdgcn_mfma_f32_16x16x32_bf16(a0, bf0[ks], acc[0][0], 0, 0, 0);
        acc[0][1] = __builtin_amdgcn_mfma_f32_16x16x32_bf16(a0, bf1[ks], acc[0][1], 0, 0, 0);
        acc[1][0] = __builtin_amdgcn_mfma_f32_16x16x32_bf16(a1, bf0[ks], acc[1][0], 0, 0, 0);
        acc[1][1] = __builtin_amdgcn_mfma_f32_16x16x32_bf16(a1, bf1[ks], acc[1][1], 0, 0, 0);
    }

    // epilogue: scatter rows to h2[b, node, :]. C/D: col = lane&15, row = quad*4 + reg
#pragma unroll
    for (int rt = 0; rt < 2; ++rt)
#pragma unroll
        for (int ct = 0; ct < 2; ++ct) {
            int col = w * 32 + ct * 16 + m;
            float bias = bc[col];
#pragma unroll
            for (int reg = 0; reg < 4; ++reg) {
                int row = rt * 16 + quad * 4 + reg;
                int node = snode[row];
                if (node >= 0)
                    h2[((size_t)b * Nn + node) * Cn + col] = fmaxf(acc[rt][ct][reg] + bias, 0.f);
            }
        }
}

// ---------------- conv 3, frontier-restricted: dst in L3-tile, gather h2 rows ----------------
__global__ __launch_bounds__(256, 4) void k_conv3L(const float* __restrict__ h2,
                                                   float* __restrict__ h3,
                                                   const unsigned short* __restrict__ Wt,
                                                   const float* __restrict__ bc,
                                                   const int* __restrict__ offs,
                                                   const int* __restrict__ ssrc,
                                                   const int* __restrict__ L3,
                                                   const int* __restrict__ meta) {
    int cnt3 = meta[2];
    int bidx = blockIdx.x;
    int b = bidx >> 5, tile = bidx & 31;
    if (tile * 32 >= cnt3) return;
    __shared__ unsigned short sSb[32 * PAD];   // 8.7 KB
    __shared__ int snode[32];
    int tid = threadIdx.x;
    if (tid < 32) {
        int ti = tile * 32 + tid;
        snode[tid] = (ti < cnt3) ? L3[ti] : -1;
    }
    __syncthreads();

    int c4 = tid & 31, u = tid >> 5;           // 4 ch per thread, rows u*4..u*4+3
    const float4* hb4 = (const float4*)(h2 + (size_t)b * (Nn * Cn));
#pragma unroll
    for (int t0 = 0; t0 < 4; ++t0) {
        int row = u * 4 + t0;
        int node = snode[row];
        float4 a = {0.f, 0.f, 0.f, 0.f};
        if (node >= 0) {
            int lo = offs[node], hi = offs[node + 1];
            for (int j = lo; j < hi; ++j) {
                float4 v = hb4[ssrc[j] * 32 + c4];
                a.x += v.x; a.y += v.y; a.z += v.z; a.w += v.w;
            }
        }
        uint2 pk;
        pk.x = f2bf(a.x) | (f2bf(a.y) << 16);
        pk.y = f2bf(a.z) | (f2bf(a.w) << 16);
        *(uint2*)&sSb[row * PAD + c4 * 4] = pk;
    }

    int lane = tid & 63, w = tid >> 6;
    int m = lane & 15, quad = lane >> 4;
    s16x8 bf0[4], bf1[4];
#pragma unroll
    for (int ks = 0; ks < 4; ++ks) {
        int ko = ks * 32 + quad * 8;
        bf0[ks] = *(const s16x8*)&Wt[(w * 32 + m) * Cn + ko];
        bf1[ks] = *(const s16x8*)&Wt[(w * 32 + 16 + m) * Cn + ko];
    }
    __syncthreads();

    f32x4 acc[2][2];
#pragma unroll
    for (int rt = 0; rt < 2; ++rt)
#pragma unroll
        for (int ct = 0; ct < 2; ++ct) acc[rt][ct] = (f32x4){0.f, 0.f, 0.f, 0.f};
#pragma unroll
    for (int ks = 0; ks < 4; ++ks) {
        int ko = ks * 32 + quad * 8;
        s16x8 a0 = *(const s16x8*)&sSb[(0 * 16 + m) * PAD + ko];
        s16x8 a1 = *(const s16x8*)&sSb[(1 * 16 + m) * PAD + ko];
        acc[0][0] = __builtin_amdgcn_mfma_f32_16x16x32_bf16(a0, bf0[ks], acc[0][0], 0, 0, 0);
        acc[0][1] = __builtin_amdgcn_mfma_f32_16x16x32_bf16(a0, bf1[ks], acc[0][1], 0, 0, 0);
        acc[1][0] = __builtin_amdgcn_mfma_f32_16x16x32_bf16(a1, bf0[ks], acc[1][0], 0, 0, 0);
        acc[1][1] = __builtin_amdgcn_mfma_f32_16x16x32_bf16(a1, bf1[ks], acc[1][1], 0, 0, 0);
    }

#pragma unroll
    for (int rt = 0; rt < 2; ++rt)
#pragma unroll
        for (int ct = 0; ct < 2; ++ct) {
            int col = w * 32 + ct * 16 + m;
            float bias = bc[col];
#pragma unroll
            for (int reg = 0; reg < 4; ++reg) {
                int row = rt * 16 + quad * 4 + reg;
                int node = snode[row];
                if (node >= 0)
                    h3[((size_t)b * Nn + node) * Cn + col] = fmaxf(acc[rt][ct][reg] + bias, 0.f);
            }
        }
}

// ---------------- conv 4 (node 0 only) + classifier, fp32 exact ----------------
// one block per sample: agg = sum_{e into node0} h3[b, src_e]; out[b] = relu(agg@Wc+bc).Wcls + bcls
__global__ __launch_bounds__(256) void k_conv4cls(const float* __restrict__ h3,
                                                  const float* __restrict__ Wc,
                                                  const float* __restrict__ bc,
                                                  const float* __restrict__ Wcls,
                                                  const float* __restrict__ bcls,
                                                  const int* __restrict__ offs,
                                                  const int* __restrict__ ssrc,
                                                  float* __restrict__ out) {
    __shared__ float sAgg[8][Cn];   // 4 KB
    __shared__ float sred[256];
    int b = blockIdx.x, tid = threadIdx.x;
    int c4 = tid & 31, u = tid >> 5;
    const float4* hb4 = (const float4*)(h3 + (size_t)b * (Nn * Cn));
    float4 a = {0.f, 0.f, 0.f, 0.f};
    int e1 = offs[1];
    for (int j = u; j < e1; j += 8) {
        float4 v = hb4[ssrc[j] * 32 + c4];
        a.x += v.x; a.y += v.y; a.z += v.z; a.w += v.w;
    }
    *(float4*)&sAgg[u][c4 * 4] = a;
    __syncthreads();
    int c = tid & 127, half = tid >> 7;
    if (tid < 128) {
        float s = sAgg[0][c];
#pragma unroll
        for (int q = 1; q < 8; ++q) s += sAgg[q][c];
        sAgg[0][c] = s;
    }
    __syncthreads();
    // split-k GEMM: 1x128 @ Wc (fp32)
    float s = 0.f;
    int k0 = half * 64;
#pragma unroll 8
    for (int k = k0; k < k0 + 64; ++k) s += sAgg[0][k] * Wc[k * Cn + c];
    sred[tid] = s;
    __syncthreads();
    if (tid < 128) {
        float val = fmaxf(sred[c] + sred[128 + c] + bc[c], 0.f);
        sred[tid] = val * Wcls[c];
    }
    __syncthreads();
    for (int st = 64; st > 0; st >>= 1) {
        if (tid < st) sred[tid] += sred[tid + st];
        __syncthreads();
    }
    if (tid == 0) out[b] = sred[0] + bcls[0];
}

extern "C" void kernel_launch(void* const* d_in, const int* in_sizes, int n_in,
                              void* d_out, int out_size, void* d_ws, size_t ws_size,
                              hipStream_t stream) {
    const float* x    = (const float*)d_in[0];
    const int*   ei32 = (const int*)d_in[1];
    const float* We   = (const float*)d_in[2];
    const float* be   = (const float*)d_in[3];
    const float* Wc   = (const float*)d_in[4];
    const float* bc   = (const float*)d_in[5];
    const float* Wcls = (const float*)d_in[6];
    const float* bcls = (const float*)d_in[7];
    float* out = (float*)d_out;

    // ---- workspace layout ----
    // 0        g       32768   (B x C fp32)
    // 32768    indeg    4096
    // 36864    meta     4096   (meta[1]=int32-detect; meta[2]=|F3|; meta[3]=|F2|)
    // 40960    offs     8192
    // 49152    cursor   4096
    // 53248    ssrc    65536
    // 118784   L3       4096
    // 122880   L2       4096
    // 126976   Wt      32768   (128x128 bf16, transposed)
    // 159744   pws    131072   (embed partials)
    // 290816   h2full  33554432 (fp32, sparse-filled at F2 rows)
    // 33845248 h3full  33554432 (fp32, sparse-filled at F3 rows)
    char* ws = (char*)d_ws;
    float*          g      = (float*)(ws + 0);
    int*            indeg  = (int*)(ws + 32768);
    int*            meta   = (int*)(ws + 36864);
    int*            offs   = (int*)(ws + 40960);
    int*            cursor = (int*)(ws + 49152);
    int*            ssrc   = (int*)(ws + 53248);
    int*            L3     = (int*)(ws + 118784);
    int*            L2     = (int*)(ws + 122880);
    unsigned short* Wt     = (unsigned short*)(ws + 126976);
    float*          pws    = (float*)(ws + 159744);
    float*          h2full = (float*)(ws + 290816);
    float*          h3full = (float*)(ws + 33845248);

    k_prep<<<132, 256, 0, stream>>>(ei32, Wc, indeg, meta, Wt);
    k_hist<<<64, 256, 0, stream>>>(ei32, meta, indeg);
    k_scan<<<1, 1024, 0, stream>>>(indeg, offs, cursor);
    k_scatter<<<64, 256, 0, stream>>>(ei32, meta, cursor, ssrc);
    k_levels<<<1, 1024, 0, stream>>>(offs, ssrc, L3, L2, meta);
    k_embedA<<<256, 256, 0, stream>>>(x, We, pws);
    k_g<<<64, 128, 0, stream>>>(pws, be, Wc, g);

    // frontier-restricted convs (fixed grids, early-exit beyond frontier counts)
    k_conv2L<<<Bn * 32, 256, 0, stream>>>(g, h2full, Wt, bc, indeg, offs, ssrc, L2, meta);
    k_conv3L<<<Bn * 32, 256, 0, stream>>>(h2full, h3full, Wt, bc, offs, ssrc, L3, meta);
    k_conv4cls<<<Bn, 256, 0, stream>>>(h3full, Wc, bc, Wcls, bcls, offs, ssrc, out);
}

// Round 8
// 138.192 us; speedup vs baseline: 1.4440x; 1.4440x over previous
//
#include <hip/hip_runtime.h>
#include <cstdint>
#include <cstddef>

constexpr int Bn = 64;     // batch
constexpr int Nn = 1024;   // nodes per graph
constexpr int Dn = 1024;   // input feature dim
constexpr int Cn = 128;    // hidden channels
constexpr int En = 16384;  // edges per graph

typedef short s16x8 __attribute__((ext_vector_type(8)));   // 8 bf16 = 4 VGPR (MFMA A/B frag)
typedef float f32x4 __attribute__((ext_vector_type(4)));   // MFMA C/D frag

__device__ __forceinline__ uint32_t f2bf(float f) {        // fp32 -> bf16 bits, RNE
    uint32_t u = __float_as_uint(f);
    return (u + 0x7fffu + ((u >> 16) & 1u)) >> 16;
}

// ---------------- prep: zero indeg | int64-detect | Wc -> bf16 transposed ----------------
// blocks 0..3: zero indeg; 4..67: detect; 68..131: wconv.
// meta[1]==1 iff int32 edge data detected (ws poisoned 0xAA; all writers store 1 -> benign race).
__global__ __launch_bounds__(256) void k_prep(const int* __restrict__ ei32,
                                              const float* __restrict__ Wc,
                                              int* __restrict__ indeg,
                                              int* __restrict__ meta,
                                              unsigned short* __restrict__ Wt) {
    int bid = blockIdx.x, tid = threadIdx.x;
    if (bid < 4) {
        indeg[bid * 256 + tid] = 0;
    } else if (bid < 68) {
        __shared__ int sh;
        if (tid == 0) sh = 0;
        __syncthreads();
        int i = (bid - 4) * 256 + tid;          // [0, 16384)
        if (ei32[2 * i + 1]) atomicOr(&sh, 1);
        __syncthreads();
        if (tid == 0 && sh) meta[1] = 1;
    } else {
        int i = (bid - 68) * 256 + tid;         // [0, 16384)
        int n = i >> 7, k = i & 127;
        Wt[i] = (unsigned short)f2bf(Wc[k * Cn + n]);
    }
}

__global__ void k_hist(const int* __restrict__ ei32, const int* __restrict__ meta,
                       int* __restrict__ indeg) {
    int e = blockIdx.x * 256 + threadIdx.x;
    bool i64 = (meta[1] != 1);
    int dst = ei32[i64 ? 2 * (En + e) : (En + e)] & (Nn - 1);
    atomicAdd(&indeg[dst], 1);
}

__global__ __launch_bounds__(1024) void k_scan(const int* __restrict__ indeg,
                                               int* __restrict__ offs,
                                               int* __restrict__ cursor) {
    __shared__ int tmp[Nn];
    int t = threadIdx.x;
    int v = indeg[t];
    tmp[t] = v;
    __syncthreads();
    for (int off = 1; off < Nn; off <<= 1) {
        int add = (t >= off) ? tmp[t - off] : 0;
        __syncthreads();
        tmp[t] += add;
        __syncthreads();
    }
    offs[t + 1] = tmp[t];
    if (t == 0) offs[0] = 0;
    cursor[t] = tmp[t] - v;   // exclusive prefix
}

__global__ void k_scatter(const int* __restrict__ ei32, const int* __restrict__ meta,
                          int* __restrict__ cursor, int* __restrict__ ssrc) {
    int e = blockIdx.x * 256 + threadIdx.x;
    bool i64 = (meta[1] != 1);
    int src = ei32[i64 ? 2 * e : e] & (Nn - 1);
    int dst = ei32[i64 ? 2 * (En + e) : (En + e)] & (Nn - 1);
    int pos = atomicAdd(&cursor[dst], 1);
    if (pos >= 0 && pos < En) ssrc[pos] = src;
}

// ---------------- frontier build: F3 = in-neighbors(node0); F2 = in-neighbors(F3) ----------------
// single block; meta[2]=|F3|, meta[3]=|F2|
__global__ __launch_bounds__(1024) void k_levels(const int* __restrict__ offs,
                                                 const int* __restrict__ ssrc,
                                                 int* __restrict__ L3,
                                                 int* __restrict__ L2,
                                                 int* __restrict__ meta) {
    __shared__ int sf3[Nn];
    __shared__ int sf2[Nn];
    __shared__ int c3, c2;
    int t = threadIdx.x;
    sf3[t] = 0; sf2[t] = 0;
    if (t == 0) { c3 = 0; c2 = 0; }
    __syncthreads();
    int e1 = offs[1];                         // edges into node 0 are [0, offs[1])
    for (int e = t; e < e1; e += 1024) sf3[ssrc[e]] = 1;
    __syncthreads();
    if (sf3[t]) {
        int lo = offs[t], hi = offs[t + 1];
        for (int e = lo; e < hi; ++e) sf2[ssrc[e]] = 1;
    }
    __syncthreads();
    if (sf3[t]) { int p = atomicAdd(&c3, 1); L3[p] = t; }
    if (sf2[t]) { int p = atomicAdd(&c2, 1); L2[p] = t; }
    __syncthreads();
    if (t == 0) { meta[2] = c3; meta[3] = c2; }
}

// ---------------- embedding stage A: partial dots ----------------
__global__ __launch_bounds__(256) void k_embedA(const float* __restrict__ x,
                                                const float* __restrict__ We,
                                                float* __restrict__ pws) {
    __shared__ float sx[256];
    __shared__ float sp[256];
    int bid = blockIdx.x, tid = threadIdx.x;
    int b = bid >> 2, q = bid & 3;
    int c = tid & 127, h2 = tid >> 7;
    sx[tid] = x[b * Dn + q * 256 + tid];
    __syncthreads();
    float acc = 0.f;
    int d0 = q * 256 + h2 * 128;
    int dl = h2 * 128;
#pragma unroll 8
    for (int i = 0; i < 128; ++i) acc += sx[dl + i] * We[(d0 + i) * Cn + c];
    sp[h2 * 128 + c] = acc;
    __syncthreads();
    if (h2 == 0) pws[(b * 4 + q) * Cn + c] = sp[c] + sp[128 + c];
}

// ---------------- stage B: blocks 0..63: g = relu(sum partials + be) @ Wc;
//                  blocks 64..191: edeg[e] = (float)indeg[ssrc[e]] ----------------
__global__ __launch_bounds__(128) void k_g(const float* __restrict__ pws,
                                           const float* __restrict__ be,
                                           const float* __restrict__ Wc,
                                           const int* __restrict__ indeg,
                                           const int* __restrict__ ssrc,
                                           float* __restrict__ g,
                                           float* __restrict__ edeg) {
    int bid = blockIdx.x, t = threadIdx.x;
    if (bid >= 64) {
        int i = (bid - 64) * 128 + t;    // [0, 16384)
        edeg[i] = (float)indeg[ssrc[i]];
        return;
    }
    __shared__ float se[Cn];
    int b = bid, c = t;
    float e = pws[(b * 4 + 0) * Cn + c] + pws[(b * 4 + 1) * Cn + c] +
              pws[(b * 4 + 2) * Cn + c] + pws[(b * 4 + 3) * Cn + c] + be[c];
    se[c] = fmaxf(e, 0.f);
    __syncthreads();
    float ga = 0.f;
#pragma unroll 8
    for (int k = 0; k < Cn; ++k) ga += se[k] * Wc[k * Cn + c];
    g[b * Cn + c] = ga;
}

constexpr int PAD = 136;     // LDS row stride in bf16 elems

// ---------------- conv 1+2 fused, frontier-restricted (tile-major grid: XCD = b%8):
// agg[dst,c] = sum_{e into dst} relu(edeg_e * g[b,c] + bc[c]); h2[b,dst,:] = relu(agg@Wc+bc) ----------------
__global__ __launch_bounds__(256, 4) void k_conv2L(const float* __restrict__ g,
                                                   float* __restrict__ h2,
                                                   const unsigned short* __restrict__ Wt,
                                                   const float* __restrict__ bc,
                                                   const int* __restrict__ offs,
                                                   const float* __restrict__ edeg,
                                                   const int* __restrict__ L2,
                                                   const int* __restrict__ meta) {
    int bidx = blockIdx.x;
    int tile = bidx >> 6, b = bidx & 63;      // tile-major: working blocks spread by b%8
    int cnt2 = meta[3];
    if (tile * 32 >= cnt2) return;
    __shared__ unsigned short sSb[32 * PAD];  // 8.7 KB
    __shared__ float sEd[32][64];             // 8 KB: staged per-row edge degrees
    __shared__ int snode[32], slo[32], scnt[32];
    int tid = threadIdx.x;
    if (tid < 32) {
        int ti = tile * 32 + tid;
        int node = (ti < cnt2) ? L2[ti] : -1;
        snode[tid] = node;
        int lo = (node >= 0) ? offs[node] : 0;
        int hi = (node >= 0) ? offs[node + 1] : 0;
        slo[tid] = lo; scnt[tid] = hi - lo;
    }
    __syncthreads();
    int w = tid >> 6, lane = tid & 63;
    // wave-local staging: wave w stages rows w*8..w*8+7 (batched, coalesced)
#pragma unroll
    for (int r = 0; r < 8; ++r) {
        int row = w * 8 + r;
        int cnt = scnt[row];
        if (lane < cnt && lane < 64) sEd[row][lane] = edeg[slo[row] + lane];
    }
    __syncthreads();

    int c2 = tid & 63;
    float gx = g[b * Cn + 2 * c2], gy = g[b * Cn + 2 * c2 + 1];
    float bx = bc[2 * c2], by = bc[2 * c2 + 1];
#pragma unroll
    for (int t0 = 0; t0 < 8; ++t0) {
        int row = w * 8 + t0;
        int cnt = scnt[row], lo = slo[row];
        float s0 = 0.f, s1 = 0.f;
        int jm = cnt < 64 ? cnt : 64;
        for (int j = 0; j < jm; ++j) {
            float d = sEd[row][j];
            s0 += fmaxf(fmaf(d, gx, bx), 0.f);
            s1 += fmaxf(fmaf(d, gy, by), 0.f);
        }
        for (int j = 64; j < cnt; ++j) {      // rare overflow tail
            float d = edeg[lo + j];
            s0 += fmaxf(fmaf(d, gx, bx), 0.f);
            s1 += fmaxf(fmaf(d, gy, by), 0.f);
        }
        *(uint32_t*)&sSb[row * PAD + 2 * c2] = f2bf(s0) | (f2bf(s1) << 16);
    }

    // B-fragments from global Wt (32 KB, L2-hot)
    int m = lane & 15, quad = lane >> 4;
    s16x8 bf0[4], bf1[4];
#pragma unroll
    for (int ks = 0; ks < 4; ++ks) {
        int ko = ks * 32 + quad * 8;
        bf0[ks] = *(const s16x8*)&Wt[(w * 32 + m) * Cn + ko];
        bf1[ks] = *(const s16x8*)&Wt[(w * 32 + 16 + m) * Cn + ko];
    }
    __syncthreads();

    f32x4 acc[2][2];
#pragma unroll
    for (int rt = 0; rt < 2; ++rt)
#pragma unroll
        for (int ct = 0; ct < 2; ++ct) acc[rt][ct] = (f32x4){0.f, 0.f, 0.f, 0.f};
#pragma unroll
    for (int ks = 0; ks < 4; ++ks) {
        int ko = ks * 32 + quad * 8;
        s16x8 a0 = *(const s16x8*)&sSb[(0 * 16 + m) * PAD + ko];
        s16x8 a1 = *(const s16x8*)&sSb[(1 * 16 + m) * PAD + ko];
        acc[0][0] = __builtin_amdgcn_mfma_f32_16x16x32_bf16(a0, bf0[ks], acc[0][0], 0, 0, 0);
        acc[0][1] = __builtin_amdgcn_mfma_f32_16x16x32_bf16(a0, bf1[ks], acc[0][1], 0, 0, 0);
        acc[1][0] = __builtin_amdgcn_mfma_f32_16x16x32_bf16(a1, bf0[ks], acc[1][0], 0, 0, 0);
        acc[1][1] = __builtin_amdgcn_mfma_f32_16x16x32_bf16(a1, bf1[ks], acc[1][1], 0, 0, 0);
    }

#pragma unroll
    for (int rt = 0; rt < 2; ++rt)
#pragma unroll
        for (int ct = 0; ct < 2; ++ct) {
            int col = w * 32 + ct * 16 + m;
            float bias = bc[col];
#pragma unroll
            for (int reg = 0; reg < 4; ++reg) {
                int row = rt * 16 + quad * 4 + reg;
                int node = snode[row];
                if (node >= 0)
                    h2[((size_t)b * Nn + node) * Cn + col] = fmaxf(acc[rt][ct][reg] + bias, 0.f);
            }
        }
}

// ---------------- conv 3, frontier-restricted (tile-major): gather h2 rows (XCD-local L2) ----------------
__global__ __launch_bounds__(256, 4) void k_conv3L(const float* __restrict__ h2,
                                                   float* __restrict__ h3,
                                                   const unsigned short* __restrict__ Wt,
                                                   const float* __restrict__ bc,
                                                   const int* __restrict__ offs,
                                                   const int* __restrict__ ssrc,
                                                   const int* __restrict__ L3,
                                                   const int* __restrict__ meta) {
    int bidx = blockIdx.x;
    int tile = bidx >> 6, b = bidx & 63;
    int cnt3 = meta[2];
    if (tile * 32 >= cnt3) return;
    __shared__ unsigned short sSb[32 * PAD];  // 8.7 KB
    __shared__ int sIdx[32][64];              // 8 KB: staged per-row source indices
    __shared__ int snode[32], slo[32], scnt[32];
    int tid = threadIdx.x;
    if (tid < 32) {
        int ti = tile * 32 + tid;
        int node = (ti < cnt3) ? L3[ti] : -1;
        snode[tid] = node;
        int lo = (node >= 0) ? offs[node] : 0;
        int hi = (node >= 0) ? offs[node + 1] : 0;
        slo[tid] = lo; scnt[tid] = hi - lo;
    }
    __syncthreads();
    int w = tid >> 6, lane = tid & 63;
#pragma unroll
    for (int r = 0; r < 8; ++r) {
        int row = w * 8 + r;
        int cnt = scnt[row];
        if (lane < cnt && lane < 64) sIdx[row][lane] = ssrc[slo[row] + lane];
    }
    __syncthreads();

    int c4 = tid & 31, u = tid >> 5;          // 4 ch per thread, rows u*4..u*4+3
    const float4* hb4 = (const float4*)(h2 + (size_t)b * (Nn * Cn));
#pragma unroll
    for (int t0 = 0; t0 < 4; ++t0) {
        int row = u * 4 + t0;
        int cnt = scnt[row], lo = slo[row];
        float4 a = {0.f, 0.f, 0.f, 0.f};
        int jm = cnt < 64 ? cnt : 64;
        for (int j = 0; j < jm; ++j) {
            float4 v = hb4[sIdx[row][j] * 32 + c4];
            a.x += v.x; a.y += v.y; a.z += v.z; a.w += v.w;
        }
        for (int j = 64; j < cnt; ++j) {      // rare overflow tail
            float4 v = hb4[ssrc[lo + j] * 32 + c4];
            a.x += v.x; a.y += v.y; a.z += v.z; a.w += v.w;
        }
        uint2 pk;
        pk.x = f2bf(a.x) | (f2bf(a.y) << 16);
        pk.y = f2bf(a.z) | (f2bf(a.w) << 16);
        *(uint2*)&sSb[row * PAD + c4 * 4] = pk;
    }

    int m = lane & 15, quad = lane >> 4;
    s16x8 bf0[4], bf1[4];
#pragma unroll
    for (int ks = 0; ks < 4; ++ks) {
        int ko = ks * 32 + quad * 8;
        bf0[ks] = *(const s16x8*)&Wt[(w * 32 + m) * Cn + ko];
        bf1[ks] = *(const s16x8*)&Wt[(w * 32 + 16 + m) * Cn + ko];
    }
    __syncthreads();

    f32x4 acc[2][2];
#pragma unroll
    for (int rt = 0; rt < 2; ++rt)
#pragma unroll
        for (int ct = 0; ct < 2; ++ct) acc[rt][ct] = (f32x4){0.f, 0.f, 0.f, 0.f};
#pragma unroll
    for (int ks = 0; ks < 4; ++ks) {
        int ko = ks * 32 + quad * 8;
        s16x8 a0 = *(const s16x8*)&sSb[(0 * 16 + m) * PAD + ko];
        s16x8 a1 = *(const s16x8*)&sSb[(1 * 16 + m) * PAD + ko];
        acc[0][0] = __builtin_amdgcn_mfma_f32_16x16x32_bf16(a0, bf0[ks], acc[0][0], 0, 0, 0);
        acc[0][1] = __builtin_amdgcn_mfma_f32_16x16x32_bf16(a0, bf1[ks], acc[0][1], 0, 0, 0);
        acc[1][0] = __builtin_amdgcn_mfma_f32_16x16x32_bf16(a1, bf0[ks], acc[1][0], 0, 0, 0);
        acc[1][1] = __builtin_amdgcn_mfma_f32_16x16x32_bf16(a1, bf1[ks], acc[1][1], 0, 0, 0);
    }

#pragma unroll
    for (int rt = 0; rt < 2; ++rt)
#pragma unroll
        for (int ct = 0; ct < 2; ++ct) {
            int col = w * 32 + ct * 16 + m;
            float bias = bc[col];
#pragma unroll
            for (int reg = 0; reg < 4; ++reg) {
                int row = rt * 16 + quad * 4 + reg;
                int node = snode[row];
                if (node >= 0)
                    h3[((size_t)b * Nn + node) * Cn + col] = fmaxf(acc[rt][ct][reg] + bias, 0.f);
            }
        }
}

// ---------------- conv 4 (node 0 only) + classifier, fp32 exact ----------------
__global__ __launch_bounds__(256) void k_conv4cls(const float* __restrict__ h3,
                                                  const float* __restrict__ Wc,
                                                  const float* __restrict__ bc,
                                                  const float* __restrict__ Wcls,
                                                  const float* __restrict__ bcls,
                                                  const int* __restrict__ offs,
                                                  const int* __restrict__ ssrc,
                                                  float* __restrict__ out) {
    __shared__ float sAgg[8][Cn];   // 4 KB
    __shared__ float sred[256];
    __shared__ int sI[256];
    int b = blockIdx.x, tid = threadIdx.x;
    int e1 = offs[1];
    int lim = e1 < 256 ? e1 : 256;
    if (tid < lim) sI[tid] = ssrc[tid];
    __syncthreads();
    int c4 = tid & 31, u = tid >> 5;
    const float4* hb4 = (const float4*)(h3 + (size_t)b * (Nn * Cn));
    float4 a = {0.f, 0.f, 0.f, 0.f};
    for (int j = u; j < lim; j += 8) {
        float4 v = hb4[sI[j] * 32 + c4];
        a.x += v.x; a.y += v.y; a.z += v.z; a.w += v.w;
    }
    for (int j = 256 + u; j < e1; j += 8) {   // rare overflow tail
        float4 v = hb4[ssrc[j] * 32 + c4];
        a.x += v.x; a.y += v.y; a.z += v.z; a.w += v.w;
    }
    *(float4*)&sAgg[u][c4 * 4] = a;
    __syncthreads();
    int c = tid & 127, half = tid >> 7;
    if (tid < 128) {
        float s = sAgg[0][c];
#pragma unroll
        for (int q = 1; q < 8; ++q) s += sAgg[q][c];
        sAgg[0][c] = s;
    }
    __syncthreads();
    // split-k GEMM: 1x128 @ Wc (fp32)
    float s = 0.f;
    int k0 = half * 64;
#pragma unroll 8
    for (int k = k0; k < k0 + 64; ++k) s += sAgg[0][k] * Wc[k * Cn + c];
    sred[tid] = s;
    __syncthreads();
    if (tid < 128) {
        float val = fmaxf(sred[c] + sred[128 + c] + bc[c], 0.f);
        sred[tid] = val * Wcls[c];
    }
    __syncthreads();
    for (int st = 64; st > 0; st >>= 1) {
        if (tid < st) sred[tid] += sred[tid + st];
        __syncthreads();
    }
    if (tid == 0) out[b] = sred[0] + bcls[0];
}

extern "C" void kernel_launch(void* const* d_in, const int* in_sizes, int n_in,
                              void* d_out, int out_size, void* d_ws, size_t ws_size,
                              hipStream_t stream) {
    const float* x    = (const float*)d_in[0];
    const int*   ei32 = (const int*)d_in[1];
    const float* We   = (const float*)d_in[2];
    const float* be   = (const float*)d_in[3];
    const float* Wc   = (const float*)d_in[4];
    const float* bc   = (const float*)d_in[5];
    const float* Wcls = (const float*)d_in[6];
    const float* bcls = (const float*)d_in[7];
    float* out = (float*)d_out;

    // ---- workspace layout ----
    // 0        g       32768   (B x C fp32)
    // 32768    indeg    4096
    // 36864    meta     4096   (meta[1]=int32-detect; meta[2]=|F3|; meta[3]=|F2|)
    // 40960    offs     8192
    // 49152    cursor   4096
    // 53248    ssrc    65536
    // 118784   edeg    65536   (fp32 degree per CSR-ordered edge)
    // 184320   L3       4096
    // 188416   L2       4096
    // 192512   Wt      32768   (128x128 bf16, transposed)
    // 225280   pws    131072   (embed partials)
    // 356352   h2full  33554432 (fp32, sparse-filled at F2 rows)
    // 33910784 h3full  33554432 (fp32, sparse-filled at F3 rows)
    char* ws = (char*)d_ws;
    float*          g      = (float*)(ws + 0);
    int*            indeg  = (int*)(ws + 32768);
    int*            meta   = (int*)(ws + 36864);
    int*            offs   = (int*)(ws + 40960);
    int*            cursor = (int*)(ws + 49152);
    int*            ssrc   = (int*)(ws + 53248);
    float*          edeg   = (float*)(ws + 118784);
    int*            L3     = (int*)(ws + 184320);
    int*            L2     = (int*)(ws + 188416);
    unsigned short* Wt     = (unsigned short*)(ws + 192512);
    float*          pws    = (float*)(ws + 225280);
    float*          h2full = (float*)(ws + 356352);
    float*          h3full = (float*)(ws + 33910784);

    k_prep<<<132, 256, 0, stream>>>(ei32, Wc, indeg, meta, Wt);
    k_hist<<<64, 256, 0, stream>>>(ei32, meta, indeg);
    k_scan<<<1, 1024, 0, stream>>>(indeg, offs, cursor);
    k_scatter<<<64, 256, 0, stream>>>(ei32, meta, cursor, ssrc);
    k_levels<<<1, 1024, 0, stream>>>(offs, ssrc, L3, L2, meta);
    k_embedA<<<256, 256, 0, stream>>>(x, We, pws);
    k_g<<<192, 128, 0, stream>>>(pws, be, Wc, indeg, ssrc, g, edeg);

    // frontier-restricted convs; tile-major grids keep sample b's blocks on XCD b%8
    k_conv2L<<<32 * Bn, 256, 0, stream>>>(g, h2full, Wt, bc, offs, edeg, L2, meta);
    k_conv3L<<<32 * Bn, 256, 0, stream>>>(h2full, h3full, Wt, bc, offs, ssrc, L3, meta);
    k_conv4cls<<<Bn, 256, 0, stream>>>(h3full, Wc, bc, Wcls, bcls, offs, ssrc, out);
}